// Round 1
// baseline (15968.945 us; speedup 1.0000x reference)
//
#include <hip/hip_runtime.h>
#include <math.h>

#define NN 100000
#define NE 1600000
#define HH 64
#define THF 0.7f
#define ATTTH 0.2f
#define EPSF 1e-5f

// ---------------- degree / norm ----------------

__global__ void fill_ones_k(float* __restrict__ p, int n) {
    int i = blockIdx.x * 256 + threadIdx.x;
    if (i < n) p[i] = 1.0f;
}

__global__ void deg_scatter_k(const int* __restrict__ dst, const int* __restrict__ mask,
                              float* __restrict__ deg, int mode) {
    int e = blockIdx.x * 256 + threadIdx.x;
    if (e >= NE) return;
    float w = mode ? (float)mask[e] : 1.0f;
    if (w != 0.0f) atomicAdd(&deg[dst[e]], w);
}

__global__ void deg_inv_k(const float* __restrict__ deg, float* __restrict__ dis,
                          float* __restrict__ dis2) {
    int i = blockIdx.x * 256 + threadIdx.x;
    if (i < NN) {
        float d = deg[i];
        dis[i] = 1.0f / sqrtf(d);
        dis2[i] = 1.0f / d;
    }
}

__global__ void norm_kk(const int* __restrict__ src, const int* __restrict__ dst,
                        const int* __restrict__ mask, const float* __restrict__ dis,
                        float* __restrict__ normv, int mode) {
    int e = blockIdx.x * 256 + threadIdx.x;
    if (e >= NE) return;
    float w = mode ? (float)mask[e] : 1.0f;
    normv[e] = dis[src[e]] * w * dis[dst[e]];
}

// ---------------- GCN: GEMM + self-loop epilogue ----------------
// out = dis2[n]*xw + b   (scatter then accumulates the neighbor agg on top)

__global__ __launch_bounds__(256) void gemm_gcn_k(const float* __restrict__ x,
                                                  const float* __restrict__ W,
                                                  const float* __restrict__ b,
                                                  const float* __restrict__ dis2,
                                                  float* __restrict__ xw,
                                                  float* __restrict__ out) {
    __shared__ float sW[64 * 64];
    __shared__ float sx[4 * 64];
    int tid = threadIdx.x;
    for (int i = tid; i < 64 * 64; i += 256) sW[i] = W[i];
    int r = tid >> 6, c = tid & 63;
    int row = blockIdx.x * 4 + r;
    sx[r * 64 + c] = x[(size_t)row * 64 + c];
    __syncthreads();
    float acc = 0.0f;
#pragma unroll
    for (int k = 0; k < 64; k++) acc += sx[r * 64 + k] * sW[k * 64 + c];
    size_t o = (size_t)row * 64 + c;
    xw[o] = acc;
    out[o] = dis2[row] * acc + b[c];
}

// ---------------- edge scatter: out[dst] += norm * xw[src] ----------------
// 16 threads per edge, float4 per thread.

__global__ __launch_bounds__(256) void scatter_k(const float* __restrict__ xw,
                                                 const float* __restrict__ normv,
                                                 const int* __restrict__ src,
                                                 const int* __restrict__ dst,
                                                 float* __restrict__ out) {
    long long t = (long long)blockIdx.x * 256 + threadIdx.x;
    int e = (int)(t >> 4);
    if (e >= NE) return;
    int q = (int)(t & 15);
    float nv = normv[e];
    if (nv == 0.0f) return;
    int s = src[e], d = dst[e];
    const float4 v = *(const float4*)&xw[(size_t)s * 64 + q * 4];
    float* o = &out[(size_t)d * 64 + q * 4];
    atomicAdd(o + 0, nv * v.x);
    atomicAdd(o + 1, nv * v.y);
    atomicAdd(o + 2, nv * v.z);
    atomicAdd(o + 3, nv * v.w);
}

// ---------------- batchnorm stats (double accumulation) ----------------
// stats[0..63] = sum, stats[64..127] = sum of squares

__global__ __launch_bounds__(256) void bn_stats_k(const float* __restrict__ x,
                                                  double* __restrict__ stats) {
    int tid = threadIdx.x;
    int c = tid & 63, g = tid >> 6;
    double s = 0.0, s2 = 0.0;
    for (int row = blockIdx.x * 4 + g; row < NN; row += gridDim.x * 4) {
        float v = x[(size_t)row * 64 + c];
        s += (double)v;
        s2 += (double)v * (double)v;
    }
    __shared__ double ls[256], ls2[256];
    ls[tid] = s; ls2[tid] = s2;
    __syncthreads();
    if (tid < 128) { ls[tid] += ls[tid + 128]; ls2[tid] += ls2[tid + 128]; }
    __syncthreads();
    if (tid < 64) {
        double a = ls[tid] + ls[tid + 64];
        double b = ls2[tid] + ls2[tid + 64];
        atomicAdd(&stats[c], a);
        atomicAdd(&stats[64 + c], b);
    }
}

// scaleshift[0..63]=scale, [64..127]=shift : bn(x) = x*scale + shift
__global__ void bn_finalize_k(const double* __restrict__ stats, const float* __restrict__ g,
                              const float* __restrict__ b, float* __restrict__ ss) {
    int c = threadIdx.x;
    if (c >= 64) return;
    double mean = stats[c] / (double)NN;
    double var = stats[64 + c] / (double)NN - mean * mean;
    float scale = (float)(1.0 / sqrt(var + (double)EPSF)) * g[c];
    float shift = b[c] - (float)mean * scale;
    ss[c] = scale;
    ss[64 + c] = shift;
}

// ---------------- fused elementwise steps ----------------

// step b: x1 = bn0(g0); lif(v_conv): spikes out, v_conv updated
__global__ void lif_conv_k(const float* __restrict__ gin, const float* __restrict__ ss,
                           float* __restrict__ vconv, float* __restrict__ spikes) {
    size_t i = (size_t)blockIdx.x * 256 + threadIdx.x;
    int c = (int)(i & 63);
    float xin = gin[i] * ss[c] + ss[64 + c];
    float v = vconv[i] + xin;
    float s = (v - THF >= 0.0f) ? 1.0f : 0.0f;
    spikes[i] = s;
    vconv[i] = v * (1.0f - s);
}

// step d: x3 = bn1(g1); pos_spike = (x3 - TH >= 0)
__global__ void bn_spike_store_k(const float* __restrict__ gin, const float* __restrict__ ss,
                                 float* __restrict__ x3, float* __restrict__ spikes) {
    size_t i = (size_t)blockIdx.x * 256 + threadIdx.x;
    int c = (int)(i & 63);
    float xv = gin[i] * ss[c] + ss[64 + c];
    x3[i] = xv;
    spikes[i] = (xv - THF >= 0.0f) ? 1.0f : 0.0f;
}

// step f: tmp = bn2(g2) + x3
__global__ void bn_add_k(const float* __restrict__ gin, const float* __restrict__ ss,
                         const float* __restrict__ x3, float* __restrict__ tmp) {
    size_t i = (size_t)blockIdx.x * 256 + threadIdx.x;
    int c = (int)(i & 63);
    tmp[i] = (gin[i] * ss[c] + ss[64 + c]) + x3[i];
}

// step g: x4 = bn3(tmp); lif(v_conv) -> x_att spikes, v_conv updated; x4 stored
__global__ void bn_lif_k(const float* __restrict__ tmp, const float* __restrict__ ss,
                         float* __restrict__ vconv, float* __restrict__ x4,
                         float* __restrict__ spikes) {
    size_t i = (size_t)blockIdx.x * 256 + threadIdx.x;
    int c = (int)(i & 63);
    float xv = tmp[i] * ss[c] + ss[64 + c];
    x4[i] = xv;
    float v = vconv[i] + xv;
    float s = (v - THF >= 0.0f) ? 1.0f : 0.0f;
    spikes[i] = s;
    vconv[i] = v * (1.0f - s);
}

// step k: q,k,v spikes from g3,g4,g5; qk = mean(q*k); att = spike(qk-ATT_TH)*v
__global__ __launch_bounds__(256) void att_k(const float* __restrict__ g3,
                                             const float* __restrict__ g4,
                                             const float* __restrict__ g5,
                                             const float* __restrict__ ss4,
                                             const float* __restrict__ ss5,
                                             const float* __restrict__ ss6,
                                             float* __restrict__ att) {
    int tid = threadIdx.x;
    int lane = tid & 63;
    int row = blockIdx.x * 4 + (tid >> 6);
    size_t i = (size_t)row * 64 + lane;
    float q = (g3[i] * ss4[lane] + ss4[64 + lane] - THF >= 0.0f) ? 1.0f : 0.0f;
    float k = (g4[i] * ss5[lane] + ss5[64 + lane] - THF >= 0.0f) ? 1.0f : 0.0f;
    float v = (g5[i] * ss6[lane] + ss6[64 + lane] - THF >= 0.0f) ? 1.0f : 0.0f;
    float p = q * k;
#pragma unroll
    for (int off = 32; off > 0; off >>= 1) p += __shfl_xor(p, off, 64);
    float qk = p * (1.0f / 64.0f);   // exact: integer/64
    float s = (qk - ATTTH >= 0.0f) ? 1.0f : 0.0f;
    att[i] = s * v;
}

// step m: tmp2 = x4 + 0.125*bn7(g6)
__global__ void bn_scale_add_k(const float* __restrict__ g6, const float* __restrict__ ss,
                               const float* __restrict__ x4, float* __restrict__ tmp2) {
    size_t i = (size_t)blockIdx.x * 256 + threadIdx.x;
    int c = (int)(i & 63);
    tmp2[i] = x4[i] + 0.125f * (g6[i] * ss[c] + ss[64 + c]);
}

// decode: z[n] = sum_h (bn8(tmp2)[n,h]) * wrow[h]
__global__ __launch_bounds__(256) void decode_k(const float* __restrict__ tmp2,
                                                const float* __restrict__ ss,
                                                const float* __restrict__ wrow,
                                                float* __restrict__ z) {
    int tid = threadIdx.x;
    int lane = tid & 63;
    int row = blockIdx.x * 4 + (tid >> 6);
    float sv = tmp2[(size_t)row * 64 + lane] * ss[lane] + ss[64 + lane];
    float p = sv * wrow[lane];
#pragma unroll
    for (int off = 32; off > 0; off >>= 1) p += __shfl_xor(p, off, 64);
    if (lane == 0) z[row] = p;
}

__global__ void wrow_k(const float* __restrict__ W_lin, float* __restrict__ wrow) {
    int h = threadIdx.x;
    if (h >= 64) return;
    float s = 0.0f;
    for (int j = 0; j < 64; j++) s += W_lin[h * 64 + j];
    wrow[h] = s;
}

// ---------------- host driver ----------------

extern "C" void kernel_launch(void* const* d_in, const int* in_sizes, int n_in,
                              void* d_out, int out_size, void* d_ws, size_t ws_size,
                              hipStream_t stream) {
    const float* x    = (const float*)d_in[0];
    const int* eidx   = (const int*)d_in[1];
    const int* emask  = (const int*)d_in[2];
    const float* Wg   = (const float*)d_in[3];
    const float* bg   = (const float*)d_in[4];
    const float* bng  = (const float*)d_in[5];
    const float* bnb  = (const float*)d_in[6];
    const float* Wlin = (const float*)d_in[7];
    float* zout = (float*)d_out;

    const int* srcp = eidx;
    const int* dstp = eidx + NE;

    const size_t NH = (size_t)NN * HH;
    float* ws = (float*)d_ws;
    float* v_conv = ws;             // NH
    float* XW = v_conv + NH;        // NH
    float* F0 = XW + NH;
    float* F1 = F0 + NH;
    float* F2 = F1 + NH;
    float* F3 = F2 + NH;
    float* F4 = F3 + NH;
    float* normv = F4 + NH;         // NE
    float* deg = normv + NE;        // NN
    float* dis = deg + NN;          // NN
    float* dis2 = dis + NN;         // NN
    double* stats = (double*)(dis2 + NN);     // 18 * 128 doubles (8B aligned)
    float* scaless = (float*)(stats + 18 * 128); // 18 * 128 floats
    float* wrow = scaless + 18 * 128;            // 64 floats

    // zero BN stat accumulators + LIF state (ws is poisoned 0xAA each call)
    hipMemsetAsync(stats, 0, 18 * 128 * sizeof(double), stream);
    hipMemsetAsync(v_conv, 0, NH * sizeof(float), stream);

    wrow_k<<<1, 64, 0, stream>>>(Wlin, wrow);

    const int NB_NODE = (NN + 255) / 256;   // per-node kernels
    const int NB_ELEM = (int)(NH / 256);    // 25000, exact
    const int NB_EDGE = NE / 256;           // 6250, exact
    const int NB_SCAT = NE * 16 / 256;      // 100000, exact
    const int NB_ROW4 = NN / 4;             // 25000, exact

    auto run_bn = [&](const float* buf, int bnglobal, int bni) {
        bn_stats_k<<<512, 256, 0, stream>>>(buf, stats + bnglobal * 128);
        bn_finalize_k<<<1, 64, 0, stream>>>(stats + bnglobal * 128, bng + bni * 64,
                                            bnb + bni * 64, scaless + bnglobal * 128);
    };

    auto enc = [&](int mode, float* zo, int bnbase) {
        // degree / normalization (deg is exactly integer-valued -> deterministic)
        fill_ones_k<<<NB_NODE, 256, 0, stream>>>(deg, NN);
        deg_scatter_k<<<NB_EDGE, 256, 0, stream>>>(dstp, emask, deg, mode);
        deg_inv_k<<<NB_NODE, 256, 0, stream>>>(deg, dis, dis2);
        norm_kk<<<NB_EDGE, 256, 0, stream>>>(srcp, dstp, emask, dis, normv, mode);

        auto gcn = [&](const float* in, int wi, float* out, int bni) {
            gemm_gcn_k<<<NB_ROW4, 256, 0, stream>>>(in, Wg + wi * 4096, bg + wi * 64,
                                                    dis2, XW, out);
            scatter_k<<<NB_SCAT, 256, 0, stream>>>(XW, normv, srcp, dstp, out);
            run_bn(out, bnbase + bni, bni);
        };
        auto SS = [&](int bni) { return scaless + (bnbase + bni) * 128; };

        gcn(x, 0, F0, 0);                                              // g0
        lif_conv_k<<<NB_ELEM, 256, 0, stream>>>(F0, SS(0), v_conv, F1); // x2 spikes
        gcn(F1, 1, F0, 1);                                             // g1
        bn_spike_store_k<<<NB_ELEM, 256, 0, stream>>>(F0, SS(1), F2, F1); // x3, pos_spike
        gcn(F1, 2, F0, 2);                                             // g2
        bn_add_k<<<NB_ELEM, 256, 0, stream>>>(F0, SS(2), F2, F1);      // tmp = x_pos + x3
        run_bn(F1, bnbase + 3, 3);
        bn_lif_k<<<NB_ELEM, 256, 0, stream>>>(F1, SS(3), v_conv, F2, F0); // x4, x_att
        gcn(F0, 3, F1, 4);                                             // g3 (q)
        gcn(F0, 4, F3, 5);                                             // g4 (k)
        gcn(F0, 5, F4, 6);                                             // g5 (v)
        att_k<<<NB_ROW4, 256, 0, stream>>>(F1, F3, F4, SS(4), SS(5), SS(6), F0); // att
        gcn(F0, 6, F1, 7);                                             // g6
        bn_scale_add_k<<<NB_ELEM, 256, 0, stream>>>(F1, SS(7), F2, F3); // tmp2
        run_bn(F3, bnbase + 8, 8);
        decode_k<<<NB_ROW4, 256, 0, stream>>>(F3, SS(8), wrow, zo);
    };

    enc(0, zout, 0);        // w = ones -> z1
    enc(1, zout + NN, 9);   // w = edge_mask, v_conv carried -> z2
}

// Round 2
// 3122.523 us; speedup vs baseline: 5.1141x; 5.1141x over previous
//
#include <hip/hip_runtime.h>
#include <math.h>

#define NN 100000
#define NE 1600000
#define HH 64
#define THF 0.7f
#define ATTTH 0.2f
#define EPSF 1e-5f
#define SCAN_B ((NN + 255) / 256)   // 391

// ---------------- degree / norm ----------------

__global__ void fill_ones_k(float* __restrict__ p, int n) {
    int i = blockIdx.x * 256 + threadIdx.x;
    if (i < n) p[i] = 1.0f;
}

__global__ void deg_scatter_k(const int* __restrict__ dst, const int* __restrict__ mask,
                              float* __restrict__ deg, int mode) {
    int e = blockIdx.x * 256 + threadIdx.x;
    if (e >= NE) return;
    float w = mode ? (float)mask[e] : 1.0f;
    if (w != 0.0f) atomicAdd(&deg[dst[e]], w);
}

__global__ void deg_inv_k(const float* __restrict__ deg, float* __restrict__ dis,
                          float* __restrict__ dis2) {
    int i = blockIdx.x * 256 + threadIdx.x;
    if (i < NN) {
        float d = deg[i];
        dis[i] = 1.0f / sqrtf(d);
        dis2[i] = 1.0f / d;
    }
}

// ---------------- CSR build (per mode: only nonzero-weight edges) ----------------

__global__ void hist_k(const int* __restrict__ dst, const int* __restrict__ mask,
                       int* __restrict__ counts, int mode) {
    int e = blockIdx.x * 256 + threadIdx.x;
    if (e >= NE) return;
    if (mode && mask[e] == 0) return;
    atomicAdd(&counts[dst[e]], 1);
}

__global__ void scan1_k(const int* __restrict__ counts, int* __restrict__ rp,
                        int* __restrict__ bsum) {
    __shared__ int ls[256];
    int i = blockIdx.x * 256 + threadIdx.x;
    int v = (i < NN) ? counts[i] : 0;
    ls[threadIdx.x] = v;
    __syncthreads();
    for (int off = 1; off < 256; off <<= 1) {
        int t = (threadIdx.x >= off) ? ls[threadIdx.x - off] : 0;
        __syncthreads();
        ls[threadIdx.x] += t;
        __syncthreads();
    }
    if (i < NN) rp[i] = ls[threadIdx.x] - v;   // block-local exclusive
    if (threadIdx.x == 255) bsum[blockIdx.x] = ls[255];
}

__global__ void scan2_k(int* __restrict__ bsum, int* __restrict__ rp) {
    // single thread: 391 elements, once per enc — negligible
    int acc = 0;
    for (int b = 0; b < SCAN_B; b++) { int t = bsum[b]; bsum[b] = acc; acc += t; }
    rp[NN] = acc;
}

__global__ void scan3_k(int* __restrict__ rp, const int* __restrict__ bsum) {
    int i = blockIdx.x * 256 + threadIdx.x;
    if (i < NN) rp[i] += bsum[blockIdx.x];
}

__global__ void csr_fill_k(const int* __restrict__ src, const int* __restrict__ dst,
                           const int* __restrict__ mask, const float* __restrict__ dis,
                           const int* __restrict__ rp, int* __restrict__ cursor,
                           int* __restrict__ cs, float* __restrict__ cn, int mode) {
    int e = blockIdx.x * 256 + threadIdx.x;
    if (e >= NE) return;
    if (mode && mask[e] == 0) return;
    int s = src[e], d = dst[e];
    int p = rp[d] + atomicAdd(&cursor[d], 1);
    cs[p] = s;
    cn[p] = dis[s] * dis[d];   // nonzero weight is always 1
}

// ---------------- GCN: GEMM + self-loop epilogue ----------------
// out = dis2[n]*xw + b ; gather_k then adds the neighbor aggregation.

__global__ __launch_bounds__(256) void gemm_gcn_k(const float* __restrict__ x,
                                                  const float* __restrict__ W,
                                                  const float* __restrict__ b,
                                                  const float* __restrict__ dis2,
                                                  float* __restrict__ xw,
                                                  float* __restrict__ out) {
    __shared__ float sW[64 * 64];
    __shared__ float sx[4 * 64];
    int tid = threadIdx.x;
    for (int i = tid; i < 64 * 64; i += 256) sW[i] = W[i];
    int r = tid >> 6, c = tid & 63;
    int row = blockIdx.x * 4 + r;
    sx[r * 64 + c] = x[(size_t)row * 64 + c];
    __syncthreads();
    float acc = 0.0f;
#pragma unroll
    for (int k = 0; k < 64; k++) acc += sx[r * 64 + k] * sW[k * 64 + c];
    size_t o = (size_t)row * 64 + c;
    xw[o] = acc;
    out[o] = dis2[row] * acc + b[c];
}

// ---------------- CSR gather: out[n] += sum_e norm_e * xw[src_e] ----------------
// One wave per node (64 lanes = 64 features). Edge meta loaded 64-wide,
// broadcast via shuffle; each edge is one coalesced 256B row read.

__global__ __launch_bounds__(256) void gather_k(const float* __restrict__ xw,
                                                const int* __restrict__ rp,
                                                const int* __restrict__ cs,
                                                const float* __restrict__ cn,
                                                float* __restrict__ out) {
    int tid = threadIdx.x;
    int lane = tid & 63;
    int nidx = blockIdx.x * 4 + (tid >> 6);
    int beg = rp[nidx], end = rp[nidx + 1];
    float acc = 0.0f;
    for (int base = beg; base < end; base += 64) {
        int cnt = min(64, end - base);
        int sj = 0; float nj = 0.0f;
        if (base + lane < end) { sj = cs[base + lane]; nj = cn[base + lane]; }
        for (int j = 0; j < cnt; j++) {
            int s = __shfl(sj, j, 64);
            float nv = __shfl(nj, j, 64);
            acc += nv * xw[(size_t)s * 64 + lane];
        }
    }
    size_t o = (size_t)nidx * 64 + lane;
    out[o] += acc;
}

// ---------------- batchnorm stats (double accumulation) ----------------

__global__ __launch_bounds__(256) void bn_stats_k(const float* __restrict__ x,
                                                  double* __restrict__ stats) {
    int tid = threadIdx.x;
    int c = tid & 63, g = tid >> 6;
    double s = 0.0, s2 = 0.0;
    for (int row = blockIdx.x * 4 + g; row < NN; row += gridDim.x * 4) {
        float v = x[(size_t)row * 64 + c];
        s += (double)v;
        s2 += (double)v * (double)v;
    }
    __shared__ double ls[256], ls2[256];
    ls[tid] = s; ls2[tid] = s2;
    __syncthreads();
    if (tid < 128) { ls[tid] += ls[tid + 128]; ls2[tid] += ls2[tid + 128]; }
    __syncthreads();
    if (tid < 64) {
        double a = ls[tid] + ls[tid + 64];
        double b = ls2[tid] + ls2[tid + 64];
        atomicAdd(&stats[c], a);
        atomicAdd(&stats[64 + c], b);
    }
}

__global__ void bn_finalize_k(const double* __restrict__ stats, const float* __restrict__ g,
                              const float* __restrict__ b, float* __restrict__ ss) {
    int c = threadIdx.x;
    if (c >= 64) return;
    double mean = stats[c] / (double)NN;
    double var = stats[64 + c] / (double)NN - mean * mean;
    float scale = (float)(1.0 / sqrt(var + (double)EPSF)) * g[c];
    float shift = b[c] - (float)mean * scale;
    ss[c] = scale;
    ss[64 + c] = shift;
}

// ---------------- fused elementwise steps ----------------

__global__ void lif_conv_k(const float* __restrict__ gin, const float* __restrict__ ss,
                           float* __restrict__ vconv, float* __restrict__ spikes) {
    size_t i = (size_t)blockIdx.x * 256 + threadIdx.x;
    int c = (int)(i & 63);
    float xin = gin[i] * ss[c] + ss[64 + c];
    float v = vconv[i] + xin;
    float s = (v - THF >= 0.0f) ? 1.0f : 0.0f;
    spikes[i] = s;
    vconv[i] = v * (1.0f - s);
}

__global__ void bn_spike_store_k(const float* __restrict__ gin, const float* __restrict__ ss,
                                 float* __restrict__ x3, float* __restrict__ spikes) {
    size_t i = (size_t)blockIdx.x * 256 + threadIdx.x;
    int c = (int)(i & 63);
    float xv = gin[i] * ss[c] + ss[64 + c];
    x3[i] = xv;
    spikes[i] = (xv - THF >= 0.0f) ? 1.0f : 0.0f;
}

__global__ void bn_add_k(const float* __restrict__ gin, const float* __restrict__ ss,
                         const float* __restrict__ x3, float* __restrict__ tmp) {
    size_t i = (size_t)blockIdx.x * 256 + threadIdx.x;
    int c = (int)(i & 63);
    tmp[i] = (gin[i] * ss[c] + ss[64 + c]) + x3[i];
}

__global__ void bn_lif_k(const float* __restrict__ tmp, const float* __restrict__ ss,
                         float* __restrict__ vconv, float* __restrict__ x4,
                         float* __restrict__ spikes) {
    size_t i = (size_t)blockIdx.x * 256 + threadIdx.x;
    int c = (int)(i & 63);
    float xv = tmp[i] * ss[c] + ss[64 + c];
    x4[i] = xv;
    float v = vconv[i] + xv;
    float s = (v - THF >= 0.0f) ? 1.0f : 0.0f;
    spikes[i] = s;
    vconv[i] = v * (1.0f - s);
}

__global__ __launch_bounds__(256) void att_k(const float* __restrict__ g3,
                                             const float* __restrict__ g4,
                                             const float* __restrict__ g5,
                                             const float* __restrict__ ss4,
                                             const float* __restrict__ ss5,
                                             const float* __restrict__ ss6,
                                             float* __restrict__ att) {
    int tid = threadIdx.x;
    int lane = tid & 63;
    int row = blockIdx.x * 4 + (tid >> 6);
    size_t i = (size_t)row * 64 + lane;
    float q = (g3[i] * ss4[lane] + ss4[64 + lane] - THF >= 0.0f) ? 1.0f : 0.0f;
    float k = (g4[i] * ss5[lane] + ss5[64 + lane] - THF >= 0.0f) ? 1.0f : 0.0f;
    float v = (g5[i] * ss6[lane] + ss6[64 + lane] - THF >= 0.0f) ? 1.0f : 0.0f;
    float p = q * k;
#pragma unroll
    for (int off = 32; off > 0; off >>= 1) p += __shfl_xor(p, off, 64);
    float qk = p * (1.0f / 64.0f);
    float s = (qk - ATTTH >= 0.0f) ? 1.0f : 0.0f;
    att[i] = s * v;
}

__global__ void bn_scale_add_k(const float* __restrict__ g6, const float* __restrict__ ss,
                               const float* __restrict__ x4, float* __restrict__ tmp2) {
    size_t i = (size_t)blockIdx.x * 256 + threadIdx.x;
    int c = (int)(i & 63);
    tmp2[i] = x4[i] + 0.125f * (g6[i] * ss[c] + ss[64 + c]);
}

__global__ __launch_bounds__(256) void decode_k(const float* __restrict__ tmp2,
                                                const float* __restrict__ ss,
                                                const float* __restrict__ wrow,
                                                float* __restrict__ z) {
    int tid = threadIdx.x;
    int lane = tid & 63;
    int row = blockIdx.x * 4 + (tid >> 6);
    float sv = tmp2[(size_t)row * 64 + lane] * ss[lane] + ss[64 + lane];
    float p = sv * wrow[lane];
#pragma unroll
    for (int off = 32; off > 0; off >>= 1) p += __shfl_xor(p, off, 64);
    if (lane == 0) z[row] = p;
}

__global__ void wrow_k(const float* __restrict__ W_lin, float* __restrict__ wrow) {
    int h = threadIdx.x;
    if (h >= 64) return;
    float s = 0.0f;
    for (int j = 0; j < 64; j++) s += W_lin[h * 64 + j];
    wrow[h] = s;
}

// ---------------- host driver ----------------

extern "C" void kernel_launch(void* const* d_in, const int* in_sizes, int n_in,
                              void* d_out, int out_size, void* d_ws, size_t ws_size,
                              hipStream_t stream) {
    const float* x    = (const float*)d_in[0];
    const int* eidx   = (const int*)d_in[1];
    const int* emask  = (const int*)d_in[2];
    const float* Wg   = (const float*)d_in[3];
    const float* bg   = (const float*)d_in[4];
    const float* bng  = (const float*)d_in[5];
    const float* bnb  = (const float*)d_in[6];
    const float* Wlin = (const float*)d_in[7];
    float* zout = (float*)d_out;

    const int* srcp = eidx;
    const int* dstp = eidx + NE;

    const size_t NH = (size_t)NN * HH;
    float* ws = (float*)d_ws;
    float* v_conv = ws;             // NH
    float* XW = v_conv + NH;        // NH
    float* F0 = XW + NH;
    float* F1 = F0 + NH;
    float* F2 = F1 + NH;
    float* F3 = F2 + NH;
    float* F4 = F3 + NH;
    float* deg = F4 + NH;           // NN
    float* dis = deg + NN;          // NN
    float* dis2 = dis + NN;         // NN
    double* stats = (double*)(dis2 + NN);          // 18*128 doubles
    float* scaless = (float*)(stats + 18 * 128);   // 18*128 floats
    float* wrow = scaless + 18 * 128;              // 64
    int* row_ptr = (int*)(wrow + 64);              // NN+1
    int* cursor  = row_ptr + NN + 2;               // NN (also histogram)
    int* bsum    = cursor + NN;                    // SCAN_B
    int* csr_src = bsum + SCAN_B + 1;              // NE
    float* csr_n = (float*)(csr_src + NE);         // NE

    hipMemsetAsync(stats, 0, 18 * 128 * sizeof(double), stream);
    hipMemsetAsync(v_conv, 0, NH * sizeof(float), stream);

    wrow_k<<<1, 64, 0, stream>>>(Wlin, wrow);

    const int NB_NODE = (NN + 255) / 256;
    const int NB_ELEM = (int)(NH / 256);
    const int NB_EDGE = NE / 256;
    const int NB_ROW4 = NN / 4;

    auto run_bn = [&](const float* buf, int bnglobal, int bni) {
        bn_stats_k<<<512, 256, 0, stream>>>(buf, stats + bnglobal * 128);
        bn_finalize_k<<<1, 64, 0, stream>>>(stats + bnglobal * 128, bng + bni * 64,
                                            bnb + bni * 64, scaless + bnglobal * 128);
    };

    auto enc = [&](int mode, float* zo, int bnbase) {
        // degree + dis
        fill_ones_k<<<NB_NODE, 256, 0, stream>>>(deg, NN);
        deg_scatter_k<<<NB_EDGE, 256, 0, stream>>>(dstp, emask, deg, mode);
        deg_inv_k<<<NB_NODE, 256, 0, stream>>>(deg, dis, dis2);
        // CSR build (nonzero-weight edges only, norm pre-baked)
        hipMemsetAsync(cursor, 0, NN * sizeof(int), stream);
        hist_k<<<NB_EDGE, 256, 0, stream>>>(dstp, emask, cursor, mode);
        scan1_k<<<SCAN_B, 256, 0, stream>>>(cursor, row_ptr, bsum);
        scan2_k<<<1, 1, 0, stream>>>(bsum, row_ptr);
        scan3_k<<<SCAN_B, 256, 0, stream>>>(row_ptr, bsum);
        hipMemsetAsync(cursor, 0, NN * sizeof(int), stream);
        csr_fill_k<<<NB_EDGE, 256, 0, stream>>>(srcp, dstp, emask, dis, row_ptr,
                                                cursor, csr_src, csr_n, mode);

        auto gcn = [&](const float* in, int wi, float* out, int bni) {
            gemm_gcn_k<<<NB_ROW4, 256, 0, stream>>>(in, Wg + wi * 4096, bg + wi * 64,
                                                    dis2, XW, out);
            gather_k<<<NB_ROW4, 256, 0, stream>>>(XW, row_ptr, csr_src, csr_n, out);
            run_bn(out, bnbase + bni, bni);
        };
        auto SS = [&](int bni) { return scaless + (bnbase + bni) * 128; };

        gcn(x, 0, F0, 0);
        lif_conv_k<<<NB_ELEM, 256, 0, stream>>>(F0, SS(0), v_conv, F1);
        gcn(F1, 1, F0, 1);
        bn_spike_store_k<<<NB_ELEM, 256, 0, stream>>>(F0, SS(1), F2, F1);
        gcn(F1, 2, F0, 2);
        bn_add_k<<<NB_ELEM, 256, 0, stream>>>(F0, SS(2), F2, F1);
        run_bn(F1, bnbase + 3, 3);
        bn_lif_k<<<NB_ELEM, 256, 0, stream>>>(F1, SS(3), v_conv, F2, F0);
        gcn(F0, 3, F1, 4);
        gcn(F0, 4, F3, 5);
        gcn(F0, 5, F4, 6);
        att_k<<<NB_ROW4, 256, 0, stream>>>(F1, F3, F4, SS(4), SS(5), SS(6), F0);
        gcn(F0, 6, F1, 7);
        bn_scale_add_k<<<NB_ELEM, 256, 0, stream>>>(F1, SS(7), F2, F3);
        run_bn(F3, bnbase + 8, 8);
        decode_k<<<NB_ROW4, 256, 0, stream>>>(F3, SS(8), wrow, zo);
    };

    enc(0, zout, 0);
    enc(1, zout + NN, 9);
}

// Round 5
// 2122.452 us; speedup vs baseline: 7.5238x; 1.4712x over previous
//
#include <hip/hip_runtime.h>
#include <math.h>
#include <stdint.h>

#define NN 100000
#define NE 1600000
#define HH 64
#define THF 0.7f
#define ATTTH 0.2f
#define EPSF 1e-5f
#define SCAN_B ((NN + 255) / 256)   // 391

typedef unsigned long long u64;

// ---------------- setup: histogram, degree, scans, CSR fill ----------------

__global__ void hist_k(const int* __restrict__ dst, const int* __restrict__ mask,
                       int* __restrict__ cnt_all, int* __restrict__ cnt_mask) {
    int e = blockIdx.x * 256 + threadIdx.x;
    if (e >= NE) return;
    int d = dst[e];
    atomicAdd(&cnt_all[d], 1);
    if (mask[e]) atomicAdd(&cnt_mask[d], 1);
}

__global__ void deg_inv_k(const int* __restrict__ cnt, float* __restrict__ dis,
                          float* __restrict__ d2i) {
    int i = blockIdx.x * 256 + threadIdx.x;
    if (i < NN) {
        float deg = (float)(cnt[i] + 1);   // +1 self loop
        dis[i] = 1.0f / sqrtf(deg);
        d2i[i] = 1.0f / deg;
    }
}

__global__ void scan1_k(const int* __restrict__ counts, int* __restrict__ rp,
                        int* __restrict__ bsum) {
    __shared__ int ls[256];
    int i = blockIdx.x * 256 + threadIdx.x;
    int v = (i < NN) ? counts[i] : 0;
    ls[threadIdx.x] = v;
    __syncthreads();
    for (int off = 1; off < 256; off <<= 1) {
        int t = (threadIdx.x >= off) ? ls[threadIdx.x - off] : 0;
        __syncthreads();
        ls[threadIdx.x] += t;
        __syncthreads();
    }
    if (i < NN) rp[i] = ls[threadIdx.x] - v;
    if (threadIdx.x == 255) bsum[blockIdx.x] = ls[255];
}

__global__ void scan2_k(int* __restrict__ bsum, int* __restrict__ rp) {
    int acc = 0;
    for (int b = 0; b < SCAN_B; b++) { int t = bsum[b]; bsum[b] = acc; acc += t; }
    rp[NN] = acc;
}

__global__ void scan3_k(int* __restrict__ rp, const int* __restrict__ bsum) {
    int i = blockIdx.x * 256 + threadIdx.x;
    if (i < NN) rp[i] += bsum[blockIdx.x];
}

// one pass fills both CSRs: em = {src, norm_bits}
__global__ void csr_fill_k(const int* __restrict__ src, const int* __restrict__ dst,
                           const int* __restrict__ mask,
                           const float* __restrict__ dis1, const float* __restrict__ dis2m,
                           const int* __restrict__ rp1, const int* __restrict__ rp2,
                           int* __restrict__ cur1, int* __restrict__ cur2,
                           int2* __restrict__ em1, int2* __restrict__ em2) {
    int e = blockIdx.x * 256 + threadIdx.x;
    if (e >= NE) return;
    int s = src[e], d = dst[e];
    float n1 = dis1[s] * dis1[d];
    int p1 = rp1[d] + atomicAdd(&cur1[d], 1);
    em1[p1] = make_int2(s, __float_as_int(n1));
    if (mask[e]) {
        float n2 = dis2m[s] * dis2m[d];
        int p2 = rp2[d] + atomicAdd(&cur2[d], 1);
        em2[p2] = make_int2(s, __float_as_int(n2));
    }
}

// ---------------- GEMM: xw = in @ W  (32 rows/block, 2x4 per thread) ----------------

__global__ __launch_bounds__(256) void gemm_k(const float* __restrict__ in,
                                              const float* __restrict__ W,
                                              float* __restrict__ xw) {
    __shared__ float sW[64 * 64];
    __shared__ float sx[32 * 65];
    int tid = threadIdx.x;
    const float4* W4 = (const float4*)W;
    float4* sW4 = (float4*)sW;
    for (int i = tid; i < 1024; i += 256) sW4[i] = W4[i];
    const float* inb = in + (size_t)blockIdx.x * 2048;
    for (int i = tid; i < 2048; i += 256) sx[(i >> 6) * 65 + (i & 63)] = inb[i];
    __syncthreads();
    int cg = tid & 15, rr = tid >> 4;
    float a0 = 0, a1 = 0, a2 = 0, a3 = 0, c0 = 0, c1 = 0, c2 = 0, c3 = 0;
#pragma unroll
    for (int k = 0; k < 64; k++) {
        float4 wv = *(const float4*)&sW[k * 64 + cg * 4];
        float xa = sx[rr * 65 + k];
        float xb = sx[(rr + 16) * 65 + k];
        a0 += xa * wv.x; a1 += xa * wv.y; a2 += xa * wv.z; a3 += xa * wv.w;
        c0 += xb * wv.x; c1 += xb * wv.y; c2 += xb * wv.z; c3 += xb * wv.w;
    }
    size_t r0 = (size_t)(blockIdx.x * 32 + rr) * 64 + cg * 4;
    size_t r1 = (size_t)(blockIdx.x * 32 + rr + 16) * 64 + cg * 4;
    *(float4*)&xw[r0] = make_float4(a0, a1, a2, a3);
    *(float4*)&xw[r1] = make_float4(c0, c1, c2, c3);
}

// ---------------- gather: out[n] = sum_e norm_e*xw[src_e] + d2i[n]*xw[n] + b ----
// One wave per node; inner loop unrolled x4 for 4 loads in flight.

__global__ __launch_bounds__(256) void gather_k(const float* __restrict__ xw,
                                                const int2* __restrict__ em,
                                                const int* __restrict__ rp,
                                                const float* __restrict__ d2i,
                                                const float* __restrict__ bias,
                                                float* __restrict__ out) {
    int tid = threadIdx.x, lane = tid & 63;
    int n = blockIdx.x * 4 + (tid >> 6);
    int beg = rp[n], end = rp[n + 1];
    float self = d2i[n] * xw[(size_t)n * 64 + lane] + bias[lane];
    float acc = 0.0f;
    for (int base = beg; base < end; base += 64) {
        int cnt = min(64, end - base);
        int2 m = make_int2(0, 0);
        if (base + lane < end) m = em[base + lane];
        int j = 0;
        for (; j + 4 <= cnt; j += 4) {
            int s0 = __shfl(m.x, j, 64);
            int s1 = __shfl(m.x, j + 1, 64);
            int s2 = __shfl(m.x, j + 2, 64);
            int s3 = __shfl(m.x, j + 3, 64);
            float n0 = __int_as_float(__shfl(m.y, j, 64));
            float n1 = __int_as_float(__shfl(m.y, j + 1, 64));
            float n2 = __int_as_float(__shfl(m.y, j + 2, 64));
            float n3 = __int_as_float(__shfl(m.y, j + 3, 64));
            float v0 = xw[(size_t)s0 * 64 + lane];
            float v1 = xw[(size_t)s1 * 64 + lane];
            float v2 = xw[(size_t)s2 * 64 + lane];
            float v3 = xw[(size_t)s3 * 64 + lane];
            acc += n0 * v0; acc += n1 * v1; acc += n2 * v2; acc += n3 * v3;
        }
        for (; j < cnt; j++) {
            int s = __shfl(m.x, j, 64);
            float nv = __int_as_float(__shfl(m.y, j, 64));
            acc += nv * xw[(size_t)s * 64 + lane];
        }
    }
    out[(size_t)n * 64 + lane] = acc + self;
}

// ---------------- batchnorm stats (double accumulation) ----------------

__global__ __launch_bounds__(256) void bn_stats_k(const float* __restrict__ x,
                                                  double* __restrict__ stats) {
    int tid = threadIdx.x;
    int c = tid & 63, g = tid >> 6;
    double s = 0.0, s2 = 0.0;
    for (int row = blockIdx.x * 4 + g; row < NN; row += gridDim.x * 4) {
        float v = x[(size_t)row * 64 + c];
        s += (double)v;
        s2 += (double)v * (double)v;
    }
    __shared__ double ls[256], ls2[256];
    ls[tid] = s; ls2[tid] = s2;
    __syncthreads();
    if (tid < 128) { ls[tid] += ls[tid + 128]; ls2[tid] += ls2[tid + 128]; }
    __syncthreads();
    if (tid < 64) {
        atomicAdd(&stats[c], ls[tid] + ls[tid + 64]);
        atomicAdd(&stats[64 + c], ls2[tid] + ls2[tid + 64]);
    }
}

// per-block bn scale/shift preamble (c < 64)
__device__ inline void bn_ss(const double* __restrict__ st, const float* __restrict__ gam,
                             const float* __restrict__ bet, int c,
                             float* __restrict__ ssc, float* __restrict__ ssh) {
    double m = st[c] * (1.0 / NN);
    double v = st[64 + c] * (1.0 / NN) - m * m;
    float scale = (float)((double)gam[c] / sqrt(v + (double)EPSF));
    ssc[c] = scale;
    ssh[c] = bet[c] - (float)m * scale;
}

// ---------------- fused elementwise steps (float spike outputs) ----------------

__global__ __launch_bounds__(256) void lif_conv_k(const float* __restrict__ G,
                                                  const double* __restrict__ st,
                                                  const float* __restrict__ gam,
                                                  const float* __restrict__ bet,
                                                  float* __restrict__ vconv,
                                                  float* __restrict__ spikes) {
    __shared__ float ssc[64], ssh[64];
    int tid = threadIdx.x;
    if (tid < 64) bn_ss(st, gam, bet, tid, ssc, ssh);
    __syncthreads();
    size_t i = (size_t)blockIdx.x * 256 + tid;
    int c = tid & 63;
    float v = vconv[i] + (G[i] * ssc[c] + ssh[c]);
    bool sp = (v - THF >= 0.0f);
    spikes[i] = sp ? 1.0f : 0.0f;
    vconv[i] = sp ? 0.0f : v;
}

__global__ __launch_bounds__(256) void bn_spike_k(const float* __restrict__ G,
                                                  const double* __restrict__ st,
                                                  const float* __restrict__ gam,
                                                  const float* __restrict__ bet,
                                                  float* __restrict__ x3,
                                                  float* __restrict__ spikes) {
    __shared__ float ssc[64], ssh[64];
    int tid = threadIdx.x;
    if (tid < 64) bn_ss(st, gam, bet, tid, ssc, ssh);
    __syncthreads();
    size_t i = (size_t)blockIdx.x * 256 + tid;
    int c = tid & 63;
    float xv = G[i] * ssc[c] + ssh[c];
    x3[i] = xv;
    spikes[i] = (xv - THF >= 0.0f) ? 1.0f : 0.0f;
}

__global__ __launch_bounds__(256) void bn_add_k(const float* __restrict__ G,
                                                const double* __restrict__ st,
                                                const float* __restrict__ gam,
                                                const float* __restrict__ bet,
                                                const float* __restrict__ x3,
                                                float* __restrict__ F) {
    __shared__ float ssc[64], ssh[64];
    int tid = threadIdx.x;
    if (tid < 64) bn_ss(st, gam, bet, tid, ssc, ssh);
    __syncthreads();
    size_t i = (size_t)blockIdx.x * 256 + tid;
    int c = tid & 63;
    F[i] = (G[i] * ssc[c] + ssh[c]) + x3[i];
}

__global__ __launch_bounds__(256) void bn_lif_k(const float* __restrict__ F,
                                                const double* __restrict__ st,
                                                const float* __restrict__ gam,
                                                const float* __restrict__ bet,
                                                float* __restrict__ vconv,
                                                float* __restrict__ x4,
                                                float* __restrict__ spikes) {
    __shared__ float ssc[64], ssh[64];
    int tid = threadIdx.x;
    if (tid < 64) bn_ss(st, gam, bet, tid, ssc, ssh);
    __syncthreads();
    size_t i = (size_t)blockIdx.x * 256 + tid;
    int c = tid & 63;
    float xv = F[i] * ssc[c] + ssh[c];
    x4[i] = xv;
    float v = vconv[i] + xv;
    bool sp = (v - THF >= 0.0f);
    spikes[i] = sp ? 1.0f : 0.0f;
    vconv[i] = sp ? 0.0f : v;
}

// qk spike per node: qs[n] = (popcount(q&k)/64 - ATT_TH >= 0)
__global__ __launch_bounds__(256) void qk_bits_k(const float* __restrict__ Gq,
                                                 const float* __restrict__ Gk,
                                                 const double* __restrict__ st4,
                                                 const double* __restrict__ st5,
                                                 const float* __restrict__ bng,
                                                 const float* __restrict__ bnb,
                                                 float* __restrict__ qs) {
    __shared__ float sc4[64], sh4[64], sc5[64], sh5[64];
    int tid = threadIdx.x;
    if (tid < 64) {
        bn_ss(st4, bng + 4 * 64, bnb + 4 * 64, tid, sc4, sh4);
        bn_ss(st5, bng + 5 * 64, bnb + 5 * 64, tid, sc5, sh5);
    }
    __syncthreads();
    size_t i = (size_t)blockIdx.x * 256 + tid;
    int c = tid & 63;
    bool qb = (Gq[i] * sc4[c] + sh4[c] - THF >= 0.0f);
    bool kb = (Gk[i] * sc5[c] + sh5[c] - THF >= 0.0f);
    int pc = __popcll(__ballot(qb && kb));
    if (c == 0)
        qs[i >> 6] = ((float)pc * (1.0f / 64.0f) - ATTTH >= 0.0f) ? 1.0f : 0.0f;
}

// att = qs[n] * v_spike
__global__ __launch_bounds__(256) void att_vk(const float* __restrict__ qs,
                                              const float* __restrict__ Gv,
                                              const double* __restrict__ st6,
                                              const float* __restrict__ gam,
                                              const float* __restrict__ bet,
                                              float* __restrict__ att) {
    __shared__ float ssc[64], ssh[64];
    int tid = threadIdx.x;
    if (tid < 64) bn_ss(st6, gam, bet, tid, ssc, ssh);
    __syncthreads();
    size_t i = (size_t)blockIdx.x * 256 + tid;
    int c = tid & 63;
    bool vb = (Gv[i] * ssc[c] + ssh[c] - THF >= 0.0f);
    att[i] = vb ? qs[i >> 6] : 0.0f;
}

__global__ __launch_bounds__(256) void bn_scale_add_k(const float* __restrict__ G,
                                                      const double* __restrict__ st,
                                                      const float* __restrict__ gam,
                                                      const float* __restrict__ bet,
                                                      const float* __restrict__ x4,
                                                      float* __restrict__ tmp2) {
    __shared__ float ssc[64], ssh[64];
    int tid = threadIdx.x;
    if (tid < 64) bn_ss(st, gam, bet, tid, ssc, ssh);
    __syncthreads();
    size_t i = (size_t)blockIdx.x * 256 + tid;
    int c = tid & 63;
    tmp2[i] = x4[i] + 0.125f * (G[i] * ssc[c] + ssh[c]);
}

__global__ __launch_bounds__(256) void decode_k(const float* __restrict__ tmp2,
                                                const double* __restrict__ st,
                                                const float* __restrict__ gam,
                                                const float* __restrict__ bet,
                                                const float* __restrict__ wrow,
                                                float* __restrict__ z) {
    __shared__ float ssc[64], ssh[64];
    int tid = threadIdx.x;
    if (tid < 64) bn_ss(st, gam, bet, tid, ssc, ssh);
    __syncthreads();
    int lane = tid & 63;
    int row = blockIdx.x * 4 + (tid >> 6);
    float sv = tmp2[(size_t)row * 64 + lane] * ssc[lane] + ssh[lane];
    float p = sv * wrow[lane];
#pragma unroll
    for (int off = 32; off > 0; off >>= 1) p += __shfl_xor(p, off, 64);
    if (lane == 0) z[row] = p;
}

__global__ void wrow_k(const float* __restrict__ W_lin, float* __restrict__ wrow) {
    int h = threadIdx.x;
    if (h >= 64) return;
    float s = 0.0f;
    for (int j = 0; j < 64; j++) s += W_lin[h * 64 + j];
    wrow[h] = s;
}

// ---------------- host driver ----------------

extern "C" void kernel_launch(void* const* d_in, const int* in_sizes, int n_in,
                              void* d_out, int out_size, void* d_ws, size_t ws_size,
                              hipStream_t stream) {
    const float* x    = (const float*)d_in[0];
    const int* eidx   = (const int*)d_in[1];
    const int* emask  = (const int*)d_in[2];
    const float* Wg   = (const float*)d_in[3];
    const float* bg   = (const float*)d_in[4];
    const float* bng  = (const float*)d_in[5];
    const float* bnb  = (const float*)d_in[6];
    const float* Wlin = (const float*)d_in[7];
    float* zout = (float*)d_out;

    const int* srcp = eidx;
    const int* dstp = eidx + NE;
    const size_t NH = (size_t)NN * HH;

    float* fb = (float*)d_ws;
    float* A = fb;                  // rotating NH buffers
    float* B = A + NH;
    float* C = B + NH;
    float* S = C + NH;
    float* D = S + NH;
    float* vconv = D + NH;
    int2* em1 = (int2*)(vconv + NH);       // NE
    int2* em2 = em1 + NE;                  // NE (only first ~half used)
    int* rp1 = (int*)(em2 + NE);           // NN+1
    int* rp2 = rp1 + NN + 2;               // NN+1
    int* cnt1 = rp2 + NN + 2;              // NN x4 contiguous (memset together)
    int* cnt2 = cnt1 + NN;
    int* cur1 = cnt2 + NN;
    int* cur2 = cur1 + NN;
    int* bsum = cur2 + NN;                 // SCAN_B
    // ALIGN to 8B for double atomics (round-4 bug: odd int offset here faulted)
    uintptr_t pa = (uintptr_t)(bsum + SCAN_B + 2);
    pa = (pa + 7) & ~(uintptr_t)7;
    double* stats = (double*)pa;                    // 18*128 doubles
    float* dis1 = (float*)(stats + 18 * 128);
    float* d21  = dis1 + NN;
    float* dis2m = d21 + NN;
    float* d22  = dis2m + NN;
    float* qs   = d22 + NN;                // NN
    float* wrow = qs + NN;                 // 64

    hipMemsetAsync(cnt1, 0, 4 * NN * sizeof(int), stream);
    hipMemsetAsync(stats, 0, 18 * 128 * sizeof(double), stream);
    hipMemsetAsync(vconv, 0, NH * sizeof(float), stream);

    const int NB_EDGE = NE / 256;       // 6250
    const int NB_NODE = SCAN_B;         // 391
    const int NB_ROW4 = NN / 4;         // 25000
    const int NB_GEMM = NN / 32;        // 3125

    wrow_k<<<1, 64, 0, stream>>>(Wlin, wrow);
    hist_k<<<NB_EDGE, 256, 0, stream>>>(dstp, emask, cnt1, cnt2);
    deg_inv_k<<<NB_NODE, 256, 0, stream>>>(cnt1, dis1, d21);
    deg_inv_k<<<NB_NODE, 256, 0, stream>>>(cnt2, dis2m, d22);
    scan1_k<<<NB_NODE, 256, 0, stream>>>(cnt1, rp1, bsum);
    scan2_k<<<1, 1, 0, stream>>>(bsum, rp1);
    scan3_k<<<NB_NODE, 256, 0, stream>>>(rp1, bsum);
    scan1_k<<<NB_NODE, 256, 0, stream>>>(cnt2, rp2, bsum);
    scan2_k<<<1, 1, 0, stream>>>(bsum, rp2);
    scan3_k<<<NB_NODE, 256, 0, stream>>>(rp2, bsum);
    csr_fill_k<<<NB_EDGE, 256, 0, stream>>>(srcp, dstp, emask, dis1, dis2m,
                                            rp1, rp2, cur1, cur2, em1, em2);

    auto enc = [&](const int2* em, const int* rp, const float* d2i, int bnbase,
                   float* zo) {
        auto ST = [&](int bni) { return stats + (bnbase + bni) * 128; };
        auto gcn = [&](const float* in, int wi, float* xwbuf, float* out) {
            gemm_k<<<NB_GEMM, 256, 0, stream>>>(in, Wg + wi * 4096, xwbuf);
            gather_k<<<NB_ROW4, 256, 0, stream>>>(xwbuf, em, rp, d2i, bg + wi * 64, out);
        };
        auto stats_run = [&](const float* buf, int bni) {
            bn_stats_k<<<512, 256, 0, stream>>>(buf, ST(bni));
        };

        gcn(x, 0, A, B); stats_run(B, 0);
        lif_conv_k<<<NB_ROW4, 256, 0, stream>>>(B, ST(0), bng, bnb, vconv, S);
        gcn(S, 1, A, B); stats_run(B, 1);
        bn_spike_k<<<NB_ROW4, 256, 0, stream>>>(B, ST(1), bng + 64, bnb + 64, C, S);
        gcn(S, 2, A, B); stats_run(B, 2);
        bn_add_k<<<NB_ROW4, 256, 0, stream>>>(B, ST(2), bng + 128, bnb + 128, C, S);
        stats_run(S, 3);
        bn_lif_k<<<NB_ROW4, 256, 0, stream>>>(S, ST(3), bng + 192, bnb + 192,
                                              vconv, C, B);   // x4=C, spikes=B
        gcn(B, 3, A, S); stats_run(S, 4);                      // q -> S
        gcn(B, 4, A, D); stats_run(D, 5);                      // k -> D
        qk_bits_k<<<NB_ROW4, 256, 0, stream>>>(S, D, ST(4), ST(5), bng, bnb, qs);
        gcn(B, 5, A, S); stats_run(S, 6);                      // v -> S
        att_vk<<<NB_ROW4, 256, 0, stream>>>(qs, S, ST(6), bng + 6 * 64, bnb + 6 * 64, B);
        gcn(B, 6, A, S); stats_run(S, 7);                      // att gcn -> S
        bn_scale_add_k<<<NB_ROW4, 256, 0, stream>>>(S, ST(7), bng + 7 * 64, bnb + 7 * 64,
                                                    C, B);     // tmp2=B
        stats_run(B, 8);
        decode_k<<<NB_ROW4, 256, 0, stream>>>(B, ST(8), bng + 8 * 64, bnb + 8 * 64,
                                              wrow, zo);
    };

    enc(em1, rp1, d21, 0, zout);
    enc(em2, rp2, d22, 9, zout + NN);
}